// Round 1
// baseline (219.433 us; speedup 1.0000x reference)
//
#include <hip/hip_runtime.h>

#define N 8192
#define D 256
#define BM 128
#define BK 32

typedef __bf16 bf16x8 __attribute__((ext_vector_type(8)));
typedef float f32x4 __attribute__((ext_vector_type(4)));

__device__ __forceinline__ unsigned short f2bf(float f) {
    unsigned u = __float_as_uint(f);
    u += 0x7FFFu + ((u >> 16) & 1u);          // round-to-nearest-even
    return (unsigned short)(u >> 16);
}

// One block per row: convert to bf16, compute fp32 squared norms of x1, x2, p.
__global__ void prep_kernel(const float* __restrict__ x1, const float* __restrict__ x2,
                            unsigned short* __restrict__ x1b, unsigned short* __restrict__ x2b,
                            unsigned short* __restrict__ pb,
                            float* __restrict__ sq1, float* __restrict__ sq2,
                            float* __restrict__ sqp) {
    const int row = blockIdx.x;
    const int t = threadIdx.x;                 // 256 threads == D
    const size_t idx = (size_t)row * D + t;
    float v1 = x1[idx], v2 = x2[idx];
    float p = 0.5f * (v1 + v2);
    x1b[idx] = f2bf(v1);
    x2b[idx] = f2bf(v2);
    pb[idx]  = f2bf(p);
    float s1 = v1 * v1, s2 = v2 * v2, sp = p * p;
    for (int o = 32; o > 0; o >>= 1) {
        s1 += __shfl_down(s1, o, 64);
        s2 += __shfl_down(s2, o, 64);
        sp += __shfl_down(sp, o, 64);
    }
    __shared__ float r1[4], r2[4], rp[4];
    const int lane = t & 63, wv = t >> 6;
    if (lane == 0) { r1[wv] = s1; r2[wv] = s2; rp[wv] = sp; }
    __syncthreads();
    if (t == 0) {
        sq1[row] = r1[0] + r1[1] + r1[2] + r1[3];
        sq2[row] = r2[0] + r2[1] + r2[2] + r2[3];
        sqp[row] = rp[0] + rp[1] + rp[2] + rp[3];
    }
}

// Fused: per 128x128 tile pair, three mini-GEMMs (x1.p^T, x2.p^T, x1.x1^T) with
// log-distance epilogue, reduced to a single double accumulator.
__global__ __launch_bounds__(256) void mqjs_main(
    const __bf16* __restrict__ x1b, const __bf16* __restrict__ x2b,
    const __bf16* __restrict__ pb,
    const float* __restrict__ sq1, const float* __restrict__ sq2,
    const float* __restrict__ sqp, double* __restrict__ acc_out) {

    __shared__ __align__(16) __bf16 As[BM * BK];
    __shared__ __align__(16) __bf16 Bs[BM * BK];
    __shared__ float sqA_s[BM], sqB_s[BM];
    __shared__ float red[4];

    const int tid = threadIdx.x;
    const int lane = tid & 63;
    const int wv = tid >> 6;
    const int wr = wv >> 1;        // wave row quadrant (0..1)
    const int wc = wv & 1;         // wave col quadrant
    const int quad = lane >> 4;
    const int l15 = lane & 15;

    const int I0 = blockIdx.y * BM;
    const int J0 = blockIdx.x * BM;

    const __bf16* Ag[3] = { x1b, x2b, x1b };
    const __bf16* Bg[3] = { pb,  pb,  x1b };
    const float* sqAg[3] = { sq1, sq2, sq1 };
    const float* sqBg[3] = { sqp, sqp, sq1 };
    const float wse = -(float)N / (float)(N - 1);

    float tsum = 0.0f;

    for (int g = 0; g < 3; ++g) {
        float wg;
        if (g < 2) {
            wg = 1.0f;
        } else {
            if (J0 < I0) break;                          // symmetric: compute upper half only
            wg = (I0 == J0) ? wse : 2.0f * wse;
        }
        const __bf16* Ap = Ag[g];
        const __bf16* Bp = Bg[g];

        __syncthreads();                                  // protect sq_s / LDS from prev epilogue
        if (tid < BM) sqA_s[tid] = sqAg[g][I0 + tid];
        else          sqB_s[tid - BM] = sqBg[g][J0 + (tid - BM)];

        f32x4 acc[4][4];
        #pragma unroll
        for (int a = 0; a < 4; ++a)
            #pragma unroll
            for (int b = 0; b < 4; ++b)
                acc[a][b] = (f32x4){0.f, 0.f, 0.f, 0.f};

        for (int kc = 0; kc < D / BK; ++kc) {
            const int k0 = kc * BK;
            // stage A/B 128x32 chunks: wave-uniform LDS base + lane*16B
            #pragma unroll
            for (int it = 0; it < 2; ++it) {
                const int gi = it * 4 + wv;               // 16-row group, 0..7
                const int row = gi * 16 + (lane >> 2);
                const int cb = (lane & 3) * 8;
                const __bf16* gpA = Ap + (size_t)(I0 + row) * D + k0 + cb;
                const __bf16* gpB = Bp + (size_t)(J0 + row) * D + k0 + cb;
                __builtin_amdgcn_global_load_lds(
                    (const __attribute__((address_space(1))) void*)gpA,
                    (__attribute__((address_space(3))) void*)(As + gi * 16 * BK), 16, 0, 0);
                __builtin_amdgcn_global_load_lds(
                    (const __attribute__((address_space(1))) void*)gpB,
                    (__attribute__((address_space(3))) void*)(Bs + gi * 16 * BK), 16, 0, 0);
            }
            __syncthreads();

            bf16x8 afr[4], bfr[4];
            #pragma unroll
            for (int t4 = 0; t4 < 4; ++t4) {
                afr[t4] = *(const bf16x8*)&As[(wr * 64 + t4 * 16 + l15) * BK + quad * 8];
                bfr[t4] = *(const bf16x8*)&Bs[(wc * 64 + t4 * 16 + l15) * BK + quad * 8];
            }
            #pragma unroll
            for (int ti = 0; ti < 4; ++ti)
                #pragma unroll
                for (int tj = 0; tj < 4; ++tj)
                    acc[ti][tj] = __builtin_amdgcn_mfma_f32_16x16x32_bf16(
                        afr[ti], bfr[tj], acc[ti][tj], 0, 0, 0);
            __syncthreads();
        }

        // epilogue: dist = sqA[i] + sqB[j] - 2*dot; sum 0.5*log(max(dist,1))
        float gsum = 0.0f;
        #pragma unroll
        for (int ti = 0; ti < 4; ++ti) {
            #pragma unroll
            for (int tj = 0; tj < 4; ++tj) {
                const float sb = sqB_s[wc * 64 + tj * 16 + l15];
                #pragma unroll
                for (int r = 0; r < 4; ++r) {
                    const float sa = sqA_s[wr * 64 + ti * 16 + quad * 4 + r];
                    const float dist = fmaf(-2.0f, acc[ti][tj][r], sa + sb);
                    gsum += __logf(fmaxf(dist, 1.0f));
                }
            }
        }
        tsum += wg * 0.5f * gsum;
    }

    for (int o = 32; o > 0; o >>= 1) tsum += __shfl_down(tsum, o, 64);
    if (lane == 0) red[wv] = tsum;
    __syncthreads();
    if (tid == 0) atomicAdd(acc_out, (double)(red[0] + red[1] + red[2] + red[3]));
}

__global__ void finalize_kernel(const double* __restrict__ acc, float* __restrict__ out) {
    out[0] = (float)(acc[0] / (double)N);
}

extern "C" void kernel_launch(void* const* d_in, const int* in_sizes, int n_in,
                              void* d_out, int out_size, void* d_ws, size_t ws_size,
                              hipStream_t stream) {
    const float* x1 = (const float*)d_in[0];
    const float* x2 = (const float*)d_in[1];

    char* ws = (char*)d_ws;
    const size_t MBYTES = (size_t)N * D * 2;              // 4 MiB per bf16 matrix
    unsigned short* x1b = (unsigned short*)(ws);
    unsigned short* x2b = (unsigned short*)(ws + MBYTES);
    unsigned short* pb  = (unsigned short*)(ws + 2 * MBYTES);
    float* sq1 = (float*)(ws + 3 * MBYTES);
    float* sq2 = (float*)(ws + 3 * MBYTES + (size_t)N * 4);
    float* sqp = (float*)(ws + 3 * MBYTES + (size_t)N * 8);
    double* acc = (double*)(ws + 3 * MBYTES + (size_t)N * 12);

    hipMemsetAsync(acc, 0, sizeof(double), stream);
    prep_kernel<<<N, 256, 0, stream>>>(x1, x2, x1b, x2b, pb, sq1, sq2, sqp);
    mqjs_main<<<dim3(N / BM, N / BM), 256, 0, stream>>>(
        (const __bf16*)x1b, (const __bf16*)x2b, (const __bf16*)pb, sq1, sq2, sqp, acc);
    finalize_kernel<<<1, 1, 0, stream>>>(acc, (float*)d_out);
}

// Round 2
// 185.149 us; speedup vs baseline: 1.1852x; 1.1852x over previous
//
#include <hip/hip_runtime.h>

#define N 8192
#define D 256
#define BM 128
#define BK 32

typedef __bf16 bf16x8 __attribute__((ext_vector_type(8)));
typedef float f32x4 __attribute__((ext_vector_type(4)));

__device__ __forceinline__ unsigned short f2bf(float f) {
    unsigned u = __float_as_uint(f);
    u += 0x7FFFu + ((u >> 16) & 1u);          // round-to-nearest-even
    return (unsigned short)(u >> 16);
}

// One block per row: convert to bf16, compute fp32 squared norms of x1, x2, p.
__global__ void prep_kernel(const float* __restrict__ x1, const float* __restrict__ x2,
                            unsigned short* __restrict__ x1b, unsigned short* __restrict__ x2b,
                            unsigned short* __restrict__ pb,
                            float* __restrict__ sq1, float* __restrict__ sq2,
                            float* __restrict__ sqp) {
    const int row = blockIdx.x;
    const int t = threadIdx.x;                 // 256 threads == D
    const size_t idx = (size_t)row * D + t;
    float v1 = x1[idx], v2 = x2[idx];
    float p = 0.5f * (v1 + v2);
    x1b[idx] = f2bf(v1);
    x2b[idx] = f2bf(v2);
    pb[idx]  = f2bf(p);
    float s1 = v1 * v1, s2 = v2 * v2, sp = p * p;
    for (int o = 32; o > 0; o >>= 1) {
        s1 += __shfl_down(s1, o, 64);
        s2 += __shfl_down(s2, o, 64);
        sp += __shfl_down(sp, o, 64);
    }
    __shared__ float r1[4], r2[4], rp[4];
    const int lane = t & 63, wv = t >> 6;
    if (lane == 0) { r1[wv] = s1; r2[wv] = s2; rp[wv] = sp; }
    __syncthreads();
    if (t == 0) {
        sq1[row] = r1[0] + r1[1] + r1[2] + r1[3];
        sq2[row] = r2[0] + r2[1] + r2[2] + r2[3];
        sqp[row] = rp[0] + rp[1] + rp[2] + rp[3];
    }
}

// log-sum epilogue for one 128x128 product tile held in acc[4][4]:
// sum over this thread's 64 entries of log(max(sqA+sqB-2*dot, 1)),
// grouped as products of 8 then one log (log(ab)=log a+log b).
__device__ __forceinline__ float tile_logsum(const f32x4 (&acc)[4][4],
                                             const float* __restrict__ sqA,
                                             const float* __restrict__ sqB,
                                             int wr, int wc, int quad, int l15) {
    float sb[4];
    #pragma unroll
    for (int tj = 0; tj < 4; ++tj) sb[tj] = sqB[wc * 64 + tj * 16 + l15];
    float s = 0.0f;
    #pragma unroll
    for (int ti = 0; ti < 4; ++ti) {
        float sa[4];
        #pragma unroll
        for (int r = 0; r < 4; ++r) sa[r] = sqA[wr * 64 + ti * 16 + quad * 4 + r];
        #pragma unroll
        for (int tjp = 0; tjp < 2; ++tjp) {
            float pr = 1.0f;
            #pragma unroll
            for (int tj = tjp * 2; tj < tjp * 2 + 2; ++tj)
                #pragma unroll
                for (int r = 0; r < 4; ++r) {
                    float d = fmaf(-2.0f, acc[ti][tj][r], sa[r] + sb[tj]);
                    pr *= fmaxf(d, 1.0f);
                }
            s += __logf(pr);       // max dist ~9e2 -> pr <= ~4e23, safe in fp32
        }
    }
    return s;
}

// Fully fused: one K-loop stages x1[I], x2[I], p[J], x1[J] tiles and accumulates
// all three products (x1.p^T, x2.p^T, x1.x1^T) before a single epilogue.
__global__ __launch_bounds__(256, 2) void mqjs_main(
    const __bf16* __restrict__ x1b, const __bf16* __restrict__ x2b,
    const __bf16* __restrict__ pb,
    const float* __restrict__ sq1, const float* __restrict__ sq2,
    const float* __restrict__ sqp, double* __restrict__ acc_out) {

    __shared__ __align__(16) __bf16 A1s[BM * BK];   // x1 I-tile
    __shared__ __align__(16) __bf16 A2s[BM * BK];   // x2 I-tile
    __shared__ __align__(16) __bf16 BPs[BM * BK];   // p  J-tile
    __shared__ __align__(16) __bf16 BXs[BM * BK];   // x1 J-tile
    __shared__ float sqa1[BM], sqa2[BM], sqbp[BM], sqbx[BM];
    __shared__ float red[4];

    const int tid = threadIdx.x;
    const int lane = tid & 63;
    const int wv = tid >> 6;
    const int wr = wv >> 1;        // wave row quadrant
    const int wc = wv & 1;         // wave col quadrant
    const int quad = lane >> 4;
    const int l15 = lane & 15;

    const int I0 = blockIdx.y * BM;
    const int J0 = blockIdx.x * BM;
    const bool doSym = (J0 >= I0);
    const float wse = -(float)N / (float)(N - 1);

    if (tid < BM) { sqa1[tid] = sq1[I0 + tid]; sqa2[tid] = sq2[I0 + tid]; }
    else { const int t = tid - BM; sqbp[t] = sqp[J0 + t]; sqbx[t] = sq1[J0 + t]; }

    // Staging lane constants. LDS slot s=(lane&3) of row r holds global chunk
    // (s - (r>>1))&3  (XOR-rotate column swizzle to kill 8-way bank aliasing).
    const int srow = lane >> 2;                                   // row in 16-row group
    const int scg  = ((lane & 3) + 4 - ((lane >> 3) & 3)) & 3;    // global chunk to fetch
    // Fragment-read byte offsets within a tile (loop-invariant; ti adds ti*1024).
    const int fch = (quad + (l15 >> 1)) & 3;                      // swizzled slot for chunk=quad
    const int fa_off = (wr * 64 + l15) * (BK * 2) + fch * 16;
    const int fb_off = (wc * 64 + l15) * (BK * 2) + fch * 16;

    f32x4 acc0[4][4], acc1[4][4], acc2[4][4];
    #pragma unroll
    for (int a = 0; a < 4; ++a)
        #pragma unroll
        for (int b = 0; b < 4; ++b) {
            acc0[a][b] = (f32x4){0.f, 0.f, 0.f, 0.f};
            acc1[a][b] = (f32x4){0.f, 0.f, 0.f, 0.f};
            acc2[a][b] = (f32x4){0.f, 0.f, 0.f, 0.f};
        }

    for (int kc = 0; kc < D / BK; ++kc) {
        const int k0 = kc * BK;
        #pragma unroll
        for (int it = 0; it < 2; ++it) {
            const int gi = it * 4 + wv;                // 16-row group 0..7
            const int row = gi * 16 + srow;
            const size_t goA = (size_t)(I0 + row) * D + k0 + scg * 8;
            const size_t goB = (size_t)(J0 + row) * D + k0 + scg * 8;
            __bf16* dA = (__bf16*)(A1s + gi * 16 * BK);
            __builtin_amdgcn_global_load_lds(
                (const __attribute__((address_space(1))) void*)(x1b + goA),
                (__attribute__((address_space(3))) void*)(A1s + gi * 16 * BK), 16, 0, 0);
            __builtin_amdgcn_global_load_lds(
                (const __attribute__((address_space(1))) void*)(x2b + goA),
                (__attribute__((address_space(3))) void*)(A2s + gi * 16 * BK), 16, 0, 0);
            __builtin_amdgcn_global_load_lds(
                (const __attribute__((address_space(1))) void*)(pb + goB),
                (__attribute__((address_space(3))) void*)(BPs + gi * 16 * BK), 16, 0, 0);
            if (doSym)
                __builtin_amdgcn_global_load_lds(
                    (const __attribute__((address_space(1))) void*)(x1b + goB),
                    (__attribute__((address_space(3))) void*)(BXs + gi * 16 * BK), 16, 0, 0);
            (void)dA;
        }
        __syncthreads();

        bf16x8 bp[4], bx[4];
        #pragma unroll
        for (int t4 = 0; t4 < 4; ++t4)
            bp[t4] = *(const bf16x8*)((const char*)BPs + fb_off + t4 * 1024);
        if (doSym) {
            #pragma unroll
            for (int t4 = 0; t4 < 4; ++t4)
                bx[t4] = *(const bf16x8*)((const char*)BXs + fb_off + t4 * 1024);
        }
        #pragma unroll
        for (int ti = 0; ti < 4; ++ti) {
            const bf16x8 a1 = *(const bf16x8*)((const char*)A1s + fa_off + ti * 1024);
            #pragma unroll
            for (int tj = 0; tj < 4; ++tj)
                acc0[ti][tj] = __builtin_amdgcn_mfma_f32_16x16x32_bf16(a1, bp[tj], acc0[ti][tj], 0, 0, 0);
            if (doSym) {
                #pragma unroll
                for (int tj = 0; tj < 4; ++tj)
                    acc2[ti][tj] = __builtin_amdgcn_mfma_f32_16x16x32_bf16(a1, bx[tj], acc2[ti][tj], 0, 0, 0);
            }
        }
        #pragma unroll
        for (int ti = 0; ti < 4; ++ti) {
            const bf16x8 a2 = *(const bf16x8*)((const char*)A2s + fa_off + ti * 1024);
            #pragma unroll
            for (int tj = 0; tj < 4; ++tj)
                acc1[ti][tj] = __builtin_amdgcn_mfma_f32_16x16x32_bf16(a2, bp[tj], acc1[ti][tj], 0, 0, 0);
        }
        __syncthreads();
    }

    float tsum = tile_logsum(acc0, sqa1, sqbp, wr, wc, quad, l15) * 0.5f
               + tile_logsum(acc1, sqa2, sqbp, wr, wc, quad, l15) * 0.5f;
    if (doSym) {
        const float wg = (I0 == J0) ? wse : 2.0f * wse;
        tsum += tile_logsum(acc2, sqa1, sqbx, wr, wc, quad, l15) * (0.5f * wg);
    }

    for (int o = 32; o > 0; o >>= 1) tsum += __shfl_down(tsum, o, 64);
    if (lane == 0) red[wv] = tsum;
    __syncthreads();
    if (tid == 0) atomicAdd(acc_out, (double)(red[0] + red[1] + red[2] + red[3]));
}

__global__ void finalize_kernel(const double* __restrict__ acc, float* __restrict__ out) {
    out[0] = (float)(acc[0] / (double)N);
}

extern "C" void kernel_launch(void* const* d_in, const int* in_sizes, int n_in,
                              void* d_out, int out_size, void* d_ws, size_t ws_size,
                              hipStream_t stream) {
    const float* x1 = (const float*)d_in[0];
    const float* x2 = (const float*)d_in[1];

    char* ws = (char*)d_ws;
    const size_t MBYTES = (size_t)N * D * 2;              // 4 MiB per bf16 matrix
    unsigned short* x1b = (unsigned short*)(ws);
    unsigned short* x2b = (unsigned short*)(ws + MBYTES);
    unsigned short* pb  = (unsigned short*)(ws + 2 * MBYTES);
    float* sq1 = (float*)(ws + 3 * MBYTES);
    float* sq2 = (float*)(ws + 3 * MBYTES + (size_t)N * 4);
    float* sqp = (float*)(ws + 3 * MBYTES + (size_t)N * 8);
    double* acc = (double*)(ws + 3 * MBYTES + (size_t)N * 12);

    hipMemsetAsync(acc, 0, sizeof(double), stream);
    prep_kernel<<<N, 256, 0, stream>>>(x1, x2, x1b, x2b, pb, sq1, sq2, sqp);
    mqjs_main<<<dim3(N / BM, N / BM), 256, 0, stream>>>(
        (const __bf16*)x1b, (const __bf16*)x2b, (const __bf16*)pb, sq1, sq2, sqp, acc);
    finalize_kernel<<<1, 1, 0, stream>>>(acc, (float*)d_out);
}

// Round 4
// 172.404 us; speedup vs baseline: 1.2728x; 1.0739x over previous
//
#include <hip/hip_runtime.h>

#define N 8192
#define D 256
#define BM 128

typedef int   i32x4 __attribute__((ext_vector_type(4)));
typedef int   i32x8 __attribute__((ext_vector_type(8)));
typedef float f32x4 __attribute__((ext_vector_type(4)));

// -------- prep: fp32 -> fp8 e4m3 (packed), norms of the DEQUANTIZED values ----
__device__ __forceinline__ unsigned pack_fp8x4(float a, float b, float c, float d) {
    unsigned lo = __builtin_amdgcn_cvt_pk_fp8_f32(a, b, 0, false);
    return __builtin_amdgcn_cvt_pk_fp8_f32(c, d, lo, true);
}
__device__ __forceinline__ float dequant_sumsq(unsigned q) {
    const float v0 = __builtin_amdgcn_cvt_f32_fp8(q, 0);
    const float v1 = __builtin_amdgcn_cvt_f32_fp8(q, 1);
    const float v2 = __builtin_amdgcn_cvt_f32_fp8(q, 2);
    const float v3 = __builtin_amdgcn_cvt_f32_fp8(q, 3);
    return fmaf(v0, v0, fmaf(v1, v1, fmaf(v2, v2, v3 * v3)));
}

// one wave per row; lane handles 4 consecutive elements (float4 in, u32 fp8x4 out)
__global__ void prep_kernel(const float* __restrict__ x1, const float* __restrict__ x2,
                            unsigned* __restrict__ x1q, unsigned* __restrict__ x2q,
                            unsigned* __restrict__ pq,
                            float* __restrict__ sq1, float* __restrict__ sq2,
                            float* __restrict__ sqp, double* __restrict__ acc) {
    const int tid = threadIdx.x, lane = tid & 63, wv = tid >> 6;
    const int row = blockIdx.x * 4 + wv;
    if (blockIdx.x == 0 && tid == 0) *acc = 0.0;   // replaces memset node
    const size_t eb = (size_t)row * D + lane * 4;
    const float4 a = *(const float4*)(x1 + eb);
    const float4 b = *(const float4*)(x2 + eb);
    const float px = 0.5f * (a.x + b.x), py = 0.5f * (a.y + b.y);
    const float pz = 0.5f * (a.z + b.z), pw = 0.5f * (a.w + b.w);
    const unsigned qa = pack_fp8x4(a.x, a.y, a.z, a.w);
    const unsigned qb = pack_fp8x4(b.x, b.y, b.z, b.w);
    const unsigned qp = pack_fp8x4(px, py, pz, pw);
    const size_t wb = (size_t)row * (D / 4) + lane;
    x1q[wb] = qa; x2q[wb] = qb; pq[wb] = qp;
    float s1 = dequant_sumsq(qa), s2 = dequant_sumsq(qb), sp = dequant_sumsq(qp);
    #pragma unroll
    for (int o = 32; o > 0; o >>= 1) {
        s1 += __shfl_down(s1, o, 64);
        s2 += __shfl_down(s2, o, 64);
        sp += __shfl_down(sp, o, 64);
    }
    if (lane == 0) { sq1[row] = s1; sq2[row] = s2; sqp[row] = sp; }
}

// -------- main ---------------------------------------------------------------
__device__ __forceinline__ f32x4 mfma8(i32x8 a, i32x8 b, f32x4 c) {
    // cbsz=0 (A fp8 e4m3), blgp=0 (B fp8), unit E8M0 scales (0x7F -> 2^0)
    return __builtin_amdgcn_mfma_scale_f32_16x16x128_f8f6f4(
        a, b, c, 0, 0, 0, 0x7F7F7F7F, 0, 0x7F7F7F7F);
}

// fragment: 32 fp8 (k-chunk quad*32) of row m; 16B blocks XOR-swizzled by row&7
__device__ __forceinline__ i32x8 read_frag(const unsigned char* Ts, int m, int quad) {
    const int r7 = m & 7;
    const i32x4 lo = *(const i32x4*)(Ts + m * 128 + ((((2 * quad)     ^ r7)) << 4));
    const i32x4 hi = *(const i32x4*)(Ts + m * 128 + ((((2 * quad + 1) ^ r7)) << 4));
    i32x8 f;
    f[0] = lo[0]; f[1] = lo[1]; f[2] = lo[2]; f[3] = lo[3];
    f[4] = hi[0]; f[5] = hi[1]; f[6] = hi[2]; f[7] = hi[3];
    return f;
}

__device__ __forceinline__ float tile_logsum(const f32x4 (&acc)[4][4],
                                             const float* __restrict__ sqA,
                                             const float* __restrict__ sqB,
                                             int wr, int wc, int quad, int l15) {
    float sb[4];
    #pragma unroll
    for (int tj = 0; tj < 4; ++tj) sb[tj] = sqB[wc * 64 + tj * 16 + l15];
    float s = 0.0f;
    #pragma unroll
    for (int ti = 0; ti < 4; ++ti) {
        float sa[4];
        #pragma unroll
        for (int r = 0; r < 4; ++r) sa[r] = sqA[wr * 64 + ti * 16 + quad * 4 + r];
        #pragma unroll
        for (int tjp = 0; tjp < 2; ++tjp) {
            float pr = 1.0f;
            #pragma unroll
            for (int tj = tjp * 2; tj < tjp * 2 + 2; ++tj)
                #pragma unroll
                for (int r = 0; r < 4; ++r) {
                    float d = fmaf(-2.0f, acc[ti][tj][r], sa[r] + sb[tj]);
                    pr *= fmaxf(d, 1.0f);
                }
            s += __logf(pr);          // dist <= ~1.5e3 -> pr <= ~2.6e25, fp32-safe
        }
    }
    return s;
}

__global__ __launch_bounds__(256, 2) void mqjs_main(
    const unsigned char* __restrict__ x1q, const unsigned char* __restrict__ x2q,
    const unsigned char* __restrict__ pq,
    const float* __restrict__ sq1, const float* __restrict__ sq2,
    const float* __restrict__ sqp, double* __restrict__ acc_out) {

    __shared__ __align__(16) unsigned char A1s[BM * 128];  // x1 I-tile (16 KB)
    __shared__ __align__(16) unsigned char A2s[BM * 128];  // x2 I-tile
    __shared__ __align__(16) unsigned char BPs[BM * 128];  // p  J-tile
    __shared__ __align__(16) unsigned char BXs[BM * 128];  // x1 J-tile
    __shared__ float sqa1[BM], sqa2[BM], sqbp[BM], sqbx[BM];
    __shared__ float red[4];

    const int tid = threadIdx.x;
    const int lane = tid & 63;
    const int wv = tid >> 6;
    const int wr = wv >> 1, wc = wv & 1;
    const int quad = lane >> 4, l15 = lane & 15;

    const int I0 = blockIdx.y * BM;
    const int J0 = blockIdx.x * BM;
    const bool doSym = (J0 >= I0);
    const float wse = -(float)N / (float)(N - 1);

    if (tid < BM) { sqa1[tid] = sq1[I0 + tid]; sqa2[tid] = sq2[I0 + tid]; }
    else { const int t = tid - BM; sqbp[t] = sqp[J0 + t]; sqbx[t] = sq1[J0 + t]; }

    // staging lane constants: wave covers 8 rows x 128B per inst; 16B blocks
    // stored at slot (lane&7), holding global block (lane&7)^(row&7)
    const int srow = lane >> 3;
    const int sblk = (lane & 7) ^ srow;

    f32x4 acc0[4][4], acc1[4][4], acc2[4][4];
    #pragma unroll
    for (int a = 0; a < 4; ++a)
        #pragma unroll
        for (int b = 0; b < 4; ++b) {
            acc0[a][b] = (f32x4){0.f, 0.f, 0.f, 0.f};
            acc1[a][b] = (f32x4){0.f, 0.f, 0.f, 0.f};
            acc2[a][b] = (f32x4){0.f, 0.f, 0.f, 0.f};
        }

    for (int kc = 0; kc < 2; ++kc) {
        const size_t kb = (size_t)kc * 128;
        #pragma unroll
        for (int it = 0; it < 4; ++it) {
            const int g = wv * 4 + it;               // 8-row group 0..15
            const int row = g * 8 + srow;
            const size_t goA = (size_t)(I0 + row) * D + kb + sblk * 16;
            const size_t goB = (size_t)(J0 + row) * D + kb + sblk * 16;
            __builtin_amdgcn_global_load_lds(
                (const __attribute__((address_space(1))) void*)(x1q + goA),
                (__attribute__((address_space(3))) void*)(A1s + g * 1024), 16, 0, 0);
            __builtin_amdgcn_global_load_lds(
                (const __attribute__((address_space(1))) void*)(x2q + goA),
                (__attribute__((address_space(3))) void*)(A2s + g * 1024), 16, 0, 0);
            __builtin_amdgcn_global_load_lds(
                (const __attribute__((address_space(1))) void*)(pq + goB),
                (__attribute__((address_space(3))) void*)(BPs + g * 1024), 16, 0, 0);
            if (doSym)
                __builtin_amdgcn_global_load_lds(
                    (const __attribute__((address_space(1))) void*)(x1q + goB),
                    (__attribute__((address_space(3))) void*)(BXs + g * 1024), 16, 0, 0);
        }
        __syncthreads();

        i32x8 bfr[4];
        #pragma unroll
        for (int tj = 0; tj < 4; ++tj)
            bfr[tj] = read_frag(BPs, wc * 64 + tj * 16 + l15, quad);
        #pragma unroll
        for (int ti = 0; ti < 4; ++ti) {
            const i32x8 a = read_frag(A1s, wr * 64 + ti * 16 + l15, quad);
            #pragma unroll
            for (int tj = 0; tj < 4; ++tj)
                acc0[ti][tj] = mfma8(a, bfr[tj], acc0[ti][tj]);
        }
        #pragma unroll
        for (int ti = 0; ti < 4; ++ti) {
            const i32x8 a = read_frag(A2s, wr * 64 + ti * 16 + l15, quad);
            #pragma unroll
            for (int tj = 0; tj < 4; ++tj)
                acc1[ti][tj] = mfma8(a, bfr[tj], acc1[ti][tj]);
        }
        if (doSym) {
            #pragma unroll
            for (int tj = 0; tj < 4; ++tj)
                bfr[tj] = read_frag(BXs, wc * 64 + tj * 16 + l15, quad);
            #pragma unroll
            for (int ti = 0; ti < 4; ++ti) {
                const i32x8 a = read_frag(A1s, wr * 64 + ti * 16 + l15, quad);
                #pragma unroll
                for (int tj = 0; tj < 4; ++tj)
                    acc2[ti][tj] = mfma8(a, bfr[tj], acc2[ti][tj]);
            }
        }
        __syncthreads();
    }

    float tsum = tile_logsum(acc0, sqa1, sqbp, wr, wc, quad, l15) * 0.5f
               + tile_logsum(acc1, sqa2, sqbp, wr, wc, quad, l15) * 0.5f;
    if (doSym) {
        const float wg = (I0 == J0) ? wse : 2.0f * wse;
        tsum += tile_logsum(acc2, sqa1, sqbx, wr, wc, quad, l15) * (0.5f * wg);
    }

    #pragma unroll
    for (int o = 32; o > 0; o >>= 1) tsum += __shfl_down(tsum, o, 64);
    if (lane == 0) red[wv] = tsum;
    __syncthreads();
    if (tid == 0) atomicAdd(acc_out, (double)(red[0] + red[1] + red[2] + red[3]));
}

__global__ void finalize_kernel(const double* __restrict__ acc, float* __restrict__ out) {
    out[0] = (float)(acc[0] / (double)N);
}

extern "C" void kernel_launch(void* const* d_in, const int* in_sizes, int n_in,
                              void* d_out, int out_size, void* d_ws, size_t ws_size,
                              hipStream_t stream) {
    const float* x1 = (const float*)d_in[0];
    const float* x2 = (const float*)d_in[1];

    char* ws = (char*)d_ws;
    const size_t MBYTES = (size_t)N * D;                  // 2 MiB per fp8 matrix
    unsigned* x1q = (unsigned*)(ws);
    unsigned* x2q = (unsigned*)(ws + MBYTES);
    unsigned* pq  = (unsigned*)(ws + 2 * MBYTES);
    float* sq1 = (float*)(ws + 3 * MBYTES);
    float* sq2 = (float*)(ws + 3 * MBYTES + (size_t)N * 4);
    float* sqp = (float*)(ws + 3 * MBYTES + (size_t)N * 8);
    double* acc = (double*)(ws + 3 * MBYTES + (size_t)N * 12);

    prep_kernel<<<N / 4, 256, 0, stream>>>(x1, x2, x1q, x2q, pq, sq1, sq2, sqp, acc);
    mqjs_main<<<dim3(N / BM, N / BM), 256, 0, stream>>>(
        (const unsigned char*)x1q, (const unsigned char*)x2q, (const unsigned char*)pq,
        sq1, sq2, sqp, acc);
    finalize_kernel<<<1, 1, 0, stream>>>(acc, (float*)d_out);
}